// Round 13
// baseline (380.543 us; speedup 1.0000x reference)
//
#include <hip/hip_runtime.h>
#include <hip/hip_fp16.h>

#define NN 50000
#define NE 800000
#define D 64
#define K1BLK 512       // k_bucket grid (k2 walk length depends on this)
#define EPB 1563        // edges per k1 block (512*1563 = 800256 >= 800000)
#define REG 1568        // per-block region stride in records (64B-aligned)
#define NSB 4096        // sub-buckets (dst>>4): 3125 used, padded to 4096
#define SNODES 16       // nodes per K2 block == sub-bucket size (100% keep)
#define LCAP 512        // dense record list cap (mean 256, sd 16 -> 16 sigma)
#define K2BLK 3125      // one block per sub-bucket; 3125*16 = 50000 exact

typedef __attribute__((ext_vector_type(8))) short short8;
typedef __attribute__((ext_vector_type(4))) float f32x4;

static __device__ __forceinline__ unsigned rne_pack(float x, float y) {
    unsigned a = __float_as_uint(x), c = __float_as_uint(y);
    a += 0x7FFFu + ((a >> 16) & 1u);
    c += 0x7FFFu + ((c >> 16) & 1u);
    return (a >> 16) | (c & 0xFFFF0000u);
}

// ---------------------------------------------------------------------------
// K1: R9's bucketizer verbatim (x2 timing probe removed; R12 measured the
// sort body at ~5us marginal).  16-node sub-buckets (dst>>4), deterministic
// layout, direct-global placement, register-built coalesced directory.
// ---------------------------------------------------------------------------
__global__ __launch_bounds__(512) void k_bucket(const int* __restrict__ dst,
                                                const int* __restrict__ src,
                                                const float* __restrict__ w,
                                                const float* __restrict__ h,
                                                const float* __restrict__ W,
                                                unsigned* __restrict__ hb,
                                                unsigned* __restrict__ Wb,
                                                unsigned* __restrict__ gidx,
                                                uint2* __restrict__ gsegB)
{
    __shared__ int hist[NSB], cur[NSB];     // 32KB
    __shared__ int wsum[8];
    int tid  = threadIdx.x;
    int blk  = blockIdx.x;
    int lane = tid & 63;
    int wid  = tid >> 6;

    // folded prep: pack h slice (and W once) to bf16, batched loads for MLP
    {
        int base = blk * 3125;                  // 512*3125 = 1,600,000 exact
        float2 v[7];
        #pragma unroll
        for (int k = 0; k < 7; k++) {
            int i = tid + k * 512;
            if (i < 3125) v[k] = ((const float2*)h)[base + i];
        }
        #pragma unroll
        for (int k = 0; k < 7; k++) {
            int i = tid + k * 512;
            if (i < 3125) hb[base + i] = rne_pack(v[k].x, v[k].y);
        }
        if (blk == 0) {
            float2 vw[8];
            #pragma unroll
            for (int k = 0; k < 8; k++)
                vw[k] = ((const float2*)W)[tid + k * 512];   // 4096 exact
            #pragma unroll
            for (int k = 0; k < 8; k++)
                Wb[tid + k * 512] = rne_pack(vw[k].x, vw[k].y);
        }
    }

    int ebase = blk * EPB;
    int epbv = NE - ebase; if (epbv > EPB) epbv = EPB;

    #pragma unroll
    for (int k = 0; k < 8; k++) hist[tid + k * 512] = 0;
    __syncthreads();

    // prefetch dst + src + w 4-deep (latency hides under hist+scan)
    int dloc[4], sloc[4];
    float wloc[4];
    #pragma unroll
    for (int k = 0; k < 4; k++) {
        int i = tid + k * 512;
        bool vld = i < epbv;
        dloc[k] = vld ? dst[ebase + i] : -1;
        sloc[k] = vld ? src[ebase + i] : 0;
        wloc[k] = vld ? w[ebase + i] : 0.f;
    }
    #pragma unroll
    for (int k = 0; k < 4; k++)
        if (dloc[k] >= 0) atomicAdd(&hist[dloc[k] >> 4], 1);
    __syncthreads();

    // exclusive scan of hist[4096]: thread owns 8 CONSECUTIVE sub-buckets
    int b[8], ts = 0;
    #pragma unroll
    for (int k = 0; k < 8; k++) { b[k] = hist[8 * tid + k]; ts += b[k]; }
    int v = ts;
    #pragma unroll
    for (int dd = 1; dd < 64; dd <<= 1) {
        int t = __shfl_up(v, dd);
        if (lane >= dd) v += t;
    }
    if (lane == 63) wsum[wid] = v;
    __syncthreads();
    if (tid < 64) {
        int s = (tid < 8) ? wsum[tid] : 0;
        #pragma unroll
        for (int dd = 1; dd < 8; dd <<= 1) {
            int t = __shfl_up(s, dd);
            if (tid >= dd) s += t;
        }
        if (tid < 8) wsum[tid] = s;
    }
    __syncthreads();
    {
        int base = v - ts + ((wid > 0) ? wsum[wid - 1] : 0);
        unsigned ent[8];
        #pragma unroll
        for (int k = 0; k < 8; k++) {
            cur[8 * tid + k] = base;
            ent[k] = (unsigned)base | ((unsigned)b[k] << 16);
            base += b[k];
        }
        // directory: two coalesced uint4 stores per thread
        uint4* gq = (uint4*)(gidx + (size_t)blk * NSB + 8 * tid);
        gq[0] = make_uint4(ent[0], ent[1], ent[2], ent[3]);
        gq[1] = make_uint4(ent[4], ent[5], ent[6], ent[7]);
    }
    __syncthreads();

    // placement DIRECT to block-private global region
    uint2* regn = gsegB + (size_t)blk * REG;
    #pragma unroll
    for (int k = 0; k < 4; k++) {
        if (dloc[k] >= 0) {
            int d = dloc[k];
            unsigned rec = ((unsigned)sloc[k] << 16) |
                           (unsigned)__half_as_ushort(__float2half(wloc[k]));
            int pos = atomicAdd(&cur[d >> 4], 1);
            regn[pos] = make_uint2(rec, (unsigned)(d & 15));
        }
    }
}

// ---------------------------------------------------------------------------
// K2 (round 13 restructure): one-THREAD-per-record aggregation.
//  A : walk directory runs, append records to a DENSE LDS list (+deg).
//  B1: thread i processes record i fully: load 128B hb row, fused
//      unpack*w -> ds_add_f32 into padded acc[16][66] (stride 66: banks
//      (2*ll+d)%32 spread; ~4-way same-address merges).  Exactly ~1
//      record/thread (256/block mean) -> perfect load balance, no per-wave
//      serial node loop, no shuffle reduces.
//  B2: mean + bf16 pack to hNl (thread = (node, 4 feats)).
//  C : proven MFMA epilogue (unchanged).
// ---------------------------------------------------------------------------
__global__ __launch_bounds__(256) void k_fused(const unsigned* __restrict__ hb,
                                               const unsigned* __restrict__ gidx,
                                               const uint2* __restrict__ gsegB,
                                               const unsigned* __restrict__ Wb,
                                               const float* __restrict__ b,
                                               float* __restrict__ out)
{
    __shared__ float accs[SNODES][66];                         // 4224B
    __shared__ uint2 list[LCAP];                               // 4096B
    __shared__ __align__(16) unsigned short hNl[SNODES * 72];  // 2304B
    __shared__ int deg[SNODES];
    __shared__ int nrec;

    int tid  = threadIdx.x;
    int lane = tid & 63;
    int wv   = __builtin_amdgcn_readfirstlane(tid >> 6);
    int nbase = blockIdx.x * SNODES;        // 3125*16 = 50000 exact, no tail
    int sb    = blockIdx.x;                 // sub-bucket == block (1:1)

    int m    = lane & 15;                   // node row within tile / B col
    int quad = lane >> 4;
    int j    = wv * 16 + m;                 // out feature owned by this lane
    int ng   = nbase + m;

    // hoisted loop-invariant loads (issue before phase A; no later stall)
    short8 bf[4];
    #pragma unroll
    for (int kk = 0; kk < 4; kk++) {
        uint4 bw = *(const uint4*)(Wb + (size_t)j * 64 + kk * 16 + quad * 4);
        bf[kk] = *(short8*)&bw;
    }
    float bv = b[j];
    uint4 t0 = *(const uint4*)(hb + (size_t)ng * 32 + 0 * 16 + quad * 4);
    uint4 t1 = *(const uint4*)(hb + (size_t)ng * 32 + 1 * 16 + quad * 4);

    // strided directory reads (row-major gidx), issued before LDS init
    unsigned e0 = gidx[(size_t)(2 * tid)     * NSB + sb];
    unsigned e1 = gidx[(size_t)(2 * tid + 1) * NSB + sb];

    // zero acc/deg/nrec
    #pragma unroll
    for (int k = 0; k < 5; k++) {
        int i = tid + k * 256;
        if (i < SNODES * 66) ((float*)accs)[i] = 0.f;
    }
    if (tid < SNODES) deg[tid] = 0;
    if (tid == 0) nrec = 0;
    __syncthreads();

    // ---- phase A: walk runs, append to dense list ----
    {
        int c0 = (int)(e0 >> 16), c1 = (int)(e1 >> 16);
        const uint2* r0 = gsegB + (size_t)(2 * tid)     * REG + (e0 & 0xFFFFu);
        const uint2* r1 = gsegB + (size_t)(2 * tid + 1) * REG + (e1 & 0xFFFFu);
        int n = max(c0, c1);
        for (int k = 0; k < n; k++) {
            uint2 a, c;
            bool va = k < c0, vb = k < c1;
            if (va) a = r0[k];
            if (vb) c = r1[k];
            if (va) {
                int p = atomicAdd(&nrec, 1);
                if (p < LCAP) list[p] = a;
                atomicAdd(&deg[a.y], 1);
            }
            if (vb) {
                int p = atomicAdd(&nrec, 1);
                if (p < LCAP) list[p] = c;
                atomicAdd(&deg[c.y], 1);
            }
        }
    }
    __syncthreads();
    int total = nrec; if (total > LCAP) total = LCAP;

    // ---- phase B1: one thread per record; fused gather+accumulate ----
    #define ACCU(u, dd)                                                     \
        atomicAdd(&ar[(dd)],     wv2 * __uint_as_float((u) << 16));         \
        atomicAdd(&ar[(dd) + 1], wv2 * __uint_as_float((u) & 0xFFFF0000u));
    for (int i = tid; i < total; i += 256) {
        uint2 e = list[i];
        float wv2 = __half2float(__ushort_as_half((unsigned short)(e.x & 0xFFFFu)));
        const uint4* row = (const uint4*)(hb + (size_t)(e.x >> 16) * 32);
        float* ar = accs[e.y];
        {   // batch 1: features 0..31 (4 x uint4, 16 VGPRs)
            uint4 r0 = row[0], r1 = row[1], r2 = row[2], r3 = row[3];
            ACCU(r0.x, 0)  ACCU(r0.y, 2)  ACCU(r0.z, 4)  ACCU(r0.w, 6)
            ACCU(r1.x, 8)  ACCU(r1.y, 10) ACCU(r1.z, 12) ACCU(r1.w, 14)
            ACCU(r2.x, 16) ACCU(r2.y, 18) ACCU(r2.z, 20) ACCU(r2.w, 22)
            ACCU(r3.x, 24) ACCU(r3.y, 26) ACCU(r3.z, 28) ACCU(r3.w, 30)
        }
        {   // batch 2: features 32..63
            uint4 r4 = row[4], r5 = row[5], r6 = row[6], r7 = row[7];
            ACCU(r4.x, 32) ACCU(r4.y, 34) ACCU(r4.z, 36) ACCU(r4.w, 38)
            ACCU(r5.x, 40) ACCU(r5.y, 42) ACCU(r5.z, 44) ACCU(r5.w, 46)
            ACCU(r6.x, 48) ACCU(r6.y, 50) ACCU(r6.z, 52) ACCU(r6.w, 54)
            ACCU(r7.x, 56) ACCU(r7.y, 58) ACCU(r7.z, 60) ACCU(r7.w, 62)
        }
    }
    #undef ACCU
    __syncthreads();

    // ---- phase B2: mean + bf16 pack (thread = node tid>>4, feats (tid&15)*4) ----
    {
        int local = tid >> 4, q2 = tid & 15;
        float inv = 1.0f / fmaxf((float)deg[local], 1.0f);
        float x0 = accs[local][q2 * 4 + 0] * inv;
        float x1 = accs[local][q2 * 4 + 1] * inv;
        float x2 = accs[local][q2 * 4 + 2] * inv;
        float x3 = accs[local][q2 * 4 + 3] * inv;
        uint2 o;
        o.x = rne_pack(x0, x1);
        o.y = rne_pack(x2, x3);
        *(uint2*)&hNl[local * 72 + q2 * 4] = o;
    }
    __syncthreads();

    // ---- phase C: MFMA GEMM; all waves share A-rows, wave = 16 out-feats --
    {
        short8 a[4];
        {
            uint4 t2 = *(const uint4*)&hNl[m * 72 + 0 * 32 + quad * 8];
            uint4 t3 = *(const uint4*)&hNl[m * 72 + 1 * 32 + quad * 8];
            a[0] = *(short8*)&t0; a[1] = *(short8*)&t1;
            a[2] = *(short8*)&t2; a[3] = *(short8*)&t3;
        }

        f32x4 acc = {bv, bv, bv, bv};
        #pragma unroll
        for (int kk = 0; kk < 4; kk++)
            acc = __builtin_amdgcn_mfma_f32_16x16x32_bf16(a[kk], bf[kk],
                                                          acc, 0, 0, 0);
        #pragma unroll
        for (int r = 0; r < 4; r++) {
            int lrow = quad * 4 + r;        // D: col=lane&15, row=quad*4+r
            out[(size_t)(nbase + lrow) * 64 + j] = acc[r];
        }
    }
}

extern "C" void kernel_launch(void* const* d_in, const int* in_sizes, int n_in,
                              void* d_out, int out_size, void* d_ws, size_t ws_size,
                              hipStream_t stream) {
    const float* h   = (const float*)d_in[0];
    const float* w   = (const float*)d_in[1];
    const int*   src = (const int*)d_in[2];
    const int*   dst = (const int*)d_in[3];
    const float* W   = (const float*)d_in[4];
    const float* b   = (const float*)d_in[5];
    float* out = (float*)d_out;

    // workspace: hb 6.4MB + Wb 16KB + gidx 8MB + gsegB 6.4MB = ~20.9MB
    char* p = (char*)d_ws;
    unsigned* hb   = (unsigned*)p;  p += (size_t)(NN * D / 2) * 4;
    unsigned* Wb   = (unsigned*)p;  p += (size_t)(64 * 128 / 2) * 4;
    unsigned* gidx = (unsigned*)p;  p += (size_t)K1BLK * NSB * 4;
    uint2* gsegB   = (uint2*)p;     // K1BLK * REG * 8 = 6,422,528 bytes

    k_bucket<<<K1BLK, 512, 0, stream>>>(dst, src, w, h, W, hb, Wb,
                                        gidx, gsegB);

    k_fused <<<K2BLK, 256, 0, stream>>>(hb, gidx, gsegB, Wb, b, out);
}

// Round 15
// 134.051 us; speedup vs baseline: 2.8388x; 2.8388x over previous
//
#include <hip/hip_runtime.h>
#include <hip/hip_fp16.h>

#define NN 50000
#define NE 800000
#define D 64
#define K1BLK 512       // k_bucket grid (k2 walk length depends on this)
#define EPB 1563        // edges per k1 block (512*1563 = 800256 >= 800000)
#define REG 1568        // per-block region stride in records (64B-aligned)
#define NSB 4096        // sub-buckets (dst>>4): 3125 used, padded to 4096
#define SNODES 16       // nodes per K2 block == sub-bucket size (100% keep)
#define SLOTS 48        // per-node slot cap; max in-degree ~37
#define K2BLK 3125      // one block per sub-bucket; 3125*16 = 50000 exact

typedef __attribute__((ext_vector_type(8))) short short8;
typedef __attribute__((ext_vector_type(4))) float f32x4;

static __device__ __forceinline__ unsigned rne_pack(float x, float y) {
    unsigned a = __float_as_uint(x), c = __float_as_uint(y);
    a += 0x7FFFu + ((a >> 16) & 1u);
    c += 0x7FFFu + ((c >> 16) & 1u);
    return (a >> 16) | (c & 0xFFFF0000u);
}

// ---------------------------------------------------------------------------
// K1: R9's bucketizer verbatim.  16-node sub-buckets (dst>>4), deterministic
// layout, direct-global placement, register-built coalesced directory.
// Measured: sort body ~5us marginal (R12), pack ~5us (R11 split null).
// ---------------------------------------------------------------------------
__global__ __launch_bounds__(512) void k_bucket(const int* __restrict__ dst,
                                                const int* __restrict__ src,
                                                const float* __restrict__ w,
                                                const float* __restrict__ h,
                                                const float* __restrict__ W,
                                                unsigned* __restrict__ hb,
                                                unsigned* __restrict__ Wb,
                                                unsigned* __restrict__ gidx,
                                                uint2* __restrict__ gsegB)
{
    __shared__ int hist[NSB], cur[NSB];     // 32KB
    __shared__ int wsum[8];
    int tid  = threadIdx.x;
    int blk  = blockIdx.x;
    int lane = tid & 63;
    int wid  = tid >> 6;

    // folded prep: pack h slice (and W once) to bf16, batched loads for MLP
    {
        int base = blk * 3125;                  // 512*3125 = 1,600,000 exact
        float2 v[7];
        #pragma unroll
        for (int k = 0; k < 7; k++) {
            int i = tid + k * 512;
            if (i < 3125) v[k] = ((const float2*)h)[base + i];
        }
        #pragma unroll
        for (int k = 0; k < 7; k++) {
            int i = tid + k * 512;
            if (i < 3125) hb[base + i] = rne_pack(v[k].x, v[k].y);
        }
        if (blk == 0) {
            float2 vw[8];
            #pragma unroll
            for (int k = 0; k < 8; k++)
                vw[k] = ((const float2*)W)[tid + k * 512];   // 4096 exact
            #pragma unroll
            for (int k = 0; k < 8; k++)
                Wb[tid + k * 512] = rne_pack(vw[k].x, vw[k].y);
        }
    }

    int ebase = blk * EPB;
    int epbv = NE - ebase; if (epbv > EPB) epbv = EPB;

    #pragma unroll
    for (int k = 0; k < 8; k++) hist[tid + k * 512] = 0;
    __syncthreads();

    // prefetch dst + src + w 4-deep (latency hides under hist+scan)
    int dloc[4], sloc[4];
    float wloc[4];
    #pragma unroll
    for (int k = 0; k < 4; k++) {
        int i = tid + k * 512;
        bool vld = i < epbv;
        dloc[k] = vld ? dst[ebase + i] : -1;
        sloc[k] = vld ? src[ebase + i] : 0;
        wloc[k] = vld ? w[ebase + i] : 0.f;
    }
    #pragma unroll
    for (int k = 0; k < 4; k++)
        if (dloc[k] >= 0) atomicAdd(&hist[dloc[k] >> 4], 1);
    __syncthreads();

    // exclusive scan of hist[4096]: thread owns 8 CONSECUTIVE sub-buckets
    int b[8], ts = 0;
    #pragma unroll
    for (int k = 0; k < 8; k++) { b[k] = hist[8 * tid + k]; ts += b[k]; }
    int v = ts;
    #pragma unroll
    for (int dd = 1; dd < 64; dd <<= 1) {
        int t = __shfl_up(v, dd);
        if (lane >= dd) v += t;
    }
    if (lane == 63) wsum[wid] = v;
    __syncthreads();
    if (tid < 64) {
        int s = (tid < 8) ? wsum[tid] : 0;
        #pragma unroll
        for (int dd = 1; dd < 8; dd <<= 1) {
            int t = __shfl_up(s, dd);
            if (tid >= dd) s += t;
        }
        if (tid < 8) wsum[tid] = s;
    }
    __syncthreads();
    {
        int base = v - ts + ((wid > 0) ? wsum[wid - 1] : 0);
        unsigned ent[8];
        #pragma unroll
        for (int k = 0; k < 8; k++) {
            cur[8 * tid + k] = base;
            ent[k] = (unsigned)base | ((unsigned)b[k] << 16);
            base += b[k];
        }
        // directory: two coalesced uint4 stores per thread
        uint4* gq = (uint4*)(gidx + (size_t)blk * NSB + 8 * tid);
        gq[0] = make_uint4(ent[0], ent[1], ent[2], ent[3]);
        gq[1] = make_uint4(ent[4], ent[5], ent[6], ent[7]);
    }
    __syncthreads();

    // placement DIRECT to block-private global region
    uint2* regn = gsegB + (size_t)blk * REG;
    #pragma unroll
    for (int k = 0; k < 4; k++) {
        if (dloc[k] >= 0) {
            int d = dloc[k];
            unsigned rec = ((unsigned)sloc[k] << 16) |
                           (unsigned)__half_as_ushort(__float2half(wloc[k]));
            int pos = atomicAdd(&cur[d >> 4], 1);
            regn[pos] = make_uint2(rec, (unsigned)(d & 15));
        }
    }
}

// ---------------------------------------------------------------------------
// K2: R9 structure (proven 16-lane-per-record coalescing; R13's thread-per-
// record A/B proved this layout superior by 7x).  Round-14 change: phase B
// processes TWO nodes per iteration with all 8 gathers issued before either
// node's accumulate chain -> 2x memory-level parallelism per wave.
// __launch_bounds__(256,8) clamps VGPR at the 64-reg cliff (R8: harmless).
// ---------------------------------------------------------------------------
__global__ __launch_bounds__(256, 8) void k_fused(const unsigned* __restrict__ hb,
                                                  const unsigned* __restrict__ gidx,
                                                  const uint2* __restrict__ gsegB,
                                                  const unsigned* __restrict__ Wb,
                                                  const float* __restrict__ b,
                                                  float* __restrict__ out)
{
    __shared__ unsigned slots[SNODES * SLOTS];                 // 3072B
    __shared__ __align__(16) unsigned short hNl[SNODES * 72];  // 2304B
    __shared__ int deg[SNODES];

    int tid  = threadIdx.x;
    int lane = tid & 63;
    int wv   = __builtin_amdgcn_readfirstlane(tid >> 6);
    int nbase = blockIdx.x * SNODES;        // 3125*16 = 50000 exact, no tail
    int sb    = blockIdx.x;                 // sub-bucket == block (1:1)

    int m    = lane & 15;                   // node row within tile / B col
    int quad = lane >> 4;
    int j    = wv * 16 + m;                 // out feature owned by this lane
    int ng   = nbase + m;

    // hoisted loop-invariant loads (issue before phase A; no later stall)
    short8 bf[4];
    #pragma unroll
    for (int kk = 0; kk < 4; kk++) {
        uint4 bw = *(const uint4*)(Wb + (size_t)j * 64 + kk * 16 + quad * 4);
        bf[kk] = *(short8*)&bw;
    }
    float bv = b[j];
    uint4 t0 = *(const uint4*)(hb + (size_t)ng * 32 + 0 * 16 + quad * 4);
    uint4 t1 = *(const uint4*)(hb + (size_t)ng * 32 + 1 * 16 + quad * 4);

    // strided directory reads (row-major gidx), issued before deg init
    unsigned e0 = gidx[(size_t)(2 * tid)     * NSB + sb];
    unsigned e1 = gidx[(size_t)(2 * tid + 1) * NSB + sb];

    if (tid < SNODES) deg[tid] = 0;
    __syncthreads();

    // ---- phase A: walk 512 lambda~0.5 runs, 2/thread, no filter ----
    {
        int c0 = (int)(e0 >> 16), c1 = (int)(e1 >> 16);
        const uint2* r0 = gsegB + (size_t)(2 * tid)     * REG + (e0 & 0xFFFFu);
        const uint2* r1 = gsegB + (size_t)(2 * tid + 1) * REG + (e1 & 0xFFFFu);
        int n = max(c0, c1);
        for (int k = 0; k < n; k++) {
            uint2 a, c;
            bool va = k < c0, vb = k < c1;
            if (va) a = r0[k];
            if (vb) c = r1[k];
            if (va) {
                int p = atomicAdd(&deg[a.y], 1);
                if (p < SLOTS) slots[a.y * SLOTS + p] = a.x;
            }
            if (vb) {
                int p = atomicAdd(&deg[c.y], 1);
                if (p < SLOTS) slots[c.y * SLOTS + p] = c.x;
            }
        }
    }
    __syncthreads();

    // ---- phase B: two nodes per iteration, 8 gathers in flight ----
    int g = lane >> 4, q = lane & 15;
    #pragma unroll 1
    for (int p2 = 0; p2 < 2; p2++) {
        int la = wv * 4 + 2 * p2;
        int lb = la + 1;
        int dga = deg[la], dgb = deg[lb];
        int ma = min(dga, SLOTS), mb = min(dgb, SLOTS);
        const unsigned* sa = &slots[la * SLOTS];
        const unsigned* sbp = &slots[lb * SLOTS];
        float4 accA = make_float4(0.f, 0.f, 0.f, 0.f);
        float4 accB = make_float4(0.f, 0.f, 0.f, 0.f);
        int n = max(ma, mb);
        #pragma unroll 1
        for (int cb = 0; cb < n; cb += 16) {
            float wa[4], wb2[4];
            uint2 ha[4], hbv[4];
            // issue ALL 8 gathers (4 per node) before any accumulate
            #pragma unroll
            for (int jj = 0; jj < 4; jj++) {
                int ii = cb + jj * 4 + g;       // <= 47 < SLOTS always
                bool va = ii < ma;
                unsigned ra = sa[ii];
                wa[jj] = va ? __half2float(__ushort_as_half(
                                  (unsigned short)(ra & 0xFFFFu))) : 0.f;
                int s = va ? (int)(ra >> 16) : 0;
                ha[jj] = *(const uint2*)(hb + (size_t)s * 32 + q * 2);
            }
            #pragma unroll
            for (int jj = 0; jj < 4; jj++) {
                int ii = cb + jj * 4 + g;
                bool vb = ii < mb;
                unsigned rb = sbp[ii];
                wb2[jj] = vb ? __half2float(__ushort_as_half(
                                   (unsigned short)(rb & 0xFFFFu))) : 0.f;
                int s = vb ? (int)(rb >> 16) : 0;
                hbv[jj] = *(const uint2*)(hb + (size_t)s * 32 + q * 2);
            }
            #pragma unroll
            for (int jj = 0; jj < 4; jj++) {
                accA.x += wa[jj] * __uint_as_float(ha[jj].x << 16);
                accA.y += wa[jj] * __uint_as_float(ha[jj].x & 0xFFFF0000u);
                accA.z += wa[jj] * __uint_as_float(ha[jj].y << 16);
                accA.w += wa[jj] * __uint_as_float(ha[jj].y & 0xFFFF0000u);
            }
            #pragma unroll
            for (int jj = 0; jj < 4; jj++) {
                accB.x += wb2[jj] * __uint_as_float(hbv[jj].x << 16);
                accB.y += wb2[jj] * __uint_as_float(hbv[jj].x & 0xFFFF0000u);
                accB.z += wb2[jj] * __uint_as_float(hbv[jj].y << 16);
                accB.w += wb2[jj] * __uint_as_float(hbv[jj].y & 0xFFFF0000u);
            }
        }
        // reduce both nodes across the 4 groups
        accA.x += __shfl_xor(accA.x, 16); accA.y += __shfl_xor(accA.y, 16);
        accA.z += __shfl_xor(accA.z, 16); accA.w += __shfl_xor(accA.w, 16);
        accA.x += __shfl_xor(accA.x, 32); accA.y += __shfl_xor(accA.y, 32);
        accA.z += __shfl_xor(accA.z, 32); accA.w += __shfl_xor(accA.w, 32);
        accB.x += __shfl_xor(accB.x, 16); accB.y += __shfl_xor(accB.y, 16);
        accB.z += __shfl_xor(accB.z, 16); accB.w += __shfl_xor(accB.w, 16);
        accB.x += __shfl_xor(accB.x, 32); accB.y += __shfl_xor(accB.y, 32);
        accB.z += __shfl_xor(accB.z, 32); accB.w += __shfl_xor(accB.w, 32);
        if (g == 0) {
            float invA = 1.0f / fmaxf((float)dga, 1.0f);
            uint2 oA;
            oA.x = rne_pack(accA.x * invA, accA.y * invA);
            oA.y = rne_pack(accA.z * invA, accA.w * invA);
            *(uint2*)&hNl[la * 72 + q * 4] = oA;
            float invB = 1.0f / fmaxf((float)dgb, 1.0f);
            uint2 oB;
            oB.x = rne_pack(accB.x * invB, accB.y * invB);
            oB.y = rne_pack(accB.z * invB, accB.w * invB);
            *(uint2*)&hNl[lb * 72 + q * 4] = oB;
        }
    }
    __syncthreads();

    // ---- phase C: MFMA GEMM; all waves share A-rows, wave = 16 out-feats --
    {
        short8 a[4];
        {
            uint4 t2 = *(const uint4*)&hNl[m * 72 + 0 * 32 + quad * 8];
            uint4 t3 = *(const uint4*)&hNl[m * 72 + 1 * 32 + quad * 8];
            a[0] = *(short8*)&t0; a[1] = *(short8*)&t1;
            a[2] = *(short8*)&t2; a[3] = *(short8*)&t3;
        }

        f32x4 acc = {bv, bv, bv, bv};
        #pragma unroll
        for (int kk = 0; kk < 4; kk++)
            acc = __builtin_amdgcn_mfma_f32_16x16x32_bf16(a[kk], bf[kk],
                                                          acc, 0, 0, 0);
        #pragma unroll
        for (int r = 0; r < 4; r++) {
            int lrow = quad * 4 + r;        // D: col=lane&15, row=quad*4+r
            out[(size_t)(nbase + lrow) * 64 + j] = acc[r];
        }
    }
}

extern "C" void kernel_launch(void* const* d_in, const int* in_sizes, int n_in,
                              void* d_out, int out_size, void* d_ws, size_t ws_size,
                              hipStream_t stream) {
    const float* h   = (const float*)d_in[0];
    const float* w   = (const float*)d_in[1];
    const int*   src = (const int*)d_in[2];
    const int*   dst = (const int*)d_in[3];
    const float* W   = (const float*)d_in[4];
    const float* b   = (const float*)d_in[5];
    float* out = (float*)d_out;

    // workspace: hb 6.4MB + Wb 16KB + gidx 8MB + gsegB 6.4MB = ~20.9MB
    char* p = (char*)d_ws;
    unsigned* hb   = (unsigned*)p;  p += (size_t)(NN * D / 2) * 4;
    unsigned* Wb   = (unsigned*)p;  p += (size_t)(64 * 128 / 2) * 4;
    unsigned* gidx = (unsigned*)p;  p += (size_t)K1BLK * NSB * 4;
    uint2* gsegB   = (uint2*)p;     // K1BLK * REG * 8 = 6,422,528 bytes

    k_bucket<<<K1BLK, 512, 0, stream>>>(dst, src, w, h, W, hb, Wb,
                                        gidx, gsegB);

    k_fused <<<K2BLK, 256, 0, stream>>>(hb, gidx, gsegB, Wb, b, out);
}

// Round 16
// 120.893 us; speedup vs baseline: 3.1478x; 1.1088x over previous
//
#include <hip/hip_runtime.h>
#include <hip/hip_fp16.h>

#define NN 50000
#define NE 800000
#define D 64
#define K1BLK 512       // k_bucket grid (k2 walk length depends on this)
#define EPB 1563        // edges per k1 block (512*1563 = 800256 >= 800000)
#define REG 1568        // per-block region stride in records (64B-aligned)
#define NSB 4096        // sub-buckets (dst>>4): 3125 used, padded to 4096
#define SNODES 16       // nodes per K2 block == sub-bucket size (100% keep)
#define SLOTS 48        // per-node slot cap; max in-degree ~37
#define K2BLK 3125      // one block per sub-bucket; 3125*16 = 50000 exact

typedef __attribute__((ext_vector_type(8))) short short8;
typedef __attribute__((ext_vector_type(4))) float f32x4;

static __device__ __forceinline__ unsigned rne_pack(float x, float y) {
    unsigned a = __float_as_uint(x), c = __float_as_uint(y);
    a += 0x7FFFu + ((a >> 16) & 1u);
    c += 0x7FFFu + ((c >> 16) & 1u);
    return (a >> 16) | (c & 0xFFFF0000u);
}

// ---------------------------------------------------------------------------
// K1: R9's bucketizer verbatim.  16-node sub-buckets (dst>>4), deterministic
// layout, direct-global placement, register-built coalesced directory.
// Measured: sort body ~5us marginal (R12), pack ~5us (R11 split null).
// ---------------------------------------------------------------------------
__global__ __launch_bounds__(512) void k_bucket(const int* __restrict__ dst,
                                                const int* __restrict__ src,
                                                const float* __restrict__ w,
                                                const float* __restrict__ h,
                                                const float* __restrict__ W,
                                                unsigned* __restrict__ hb,
                                                unsigned* __restrict__ Wb,
                                                unsigned* __restrict__ gidx,
                                                uint2* __restrict__ gsegB)
{
    __shared__ int hist[NSB], cur[NSB];     // 32KB
    __shared__ int wsum[8];
    int tid  = threadIdx.x;
    int blk  = blockIdx.x;
    int lane = tid & 63;
    int wid  = tid >> 6;

    // folded prep: pack h slice (and W once) to bf16, batched loads for MLP
    {
        int base = blk * 3125;                  // 512*3125 = 1,600,000 exact
        float2 v[7];
        #pragma unroll
        for (int k = 0; k < 7; k++) {
            int i = tid + k * 512;
            if (i < 3125) v[k] = ((const float2*)h)[base + i];
        }
        #pragma unroll
        for (int k = 0; k < 7; k++) {
            int i = tid + k * 512;
            if (i < 3125) hb[base + i] = rne_pack(v[k].x, v[k].y);
        }
        if (blk == 0) {
            float2 vw[8];
            #pragma unroll
            for (int k = 0; k < 8; k++)
                vw[k] = ((const float2*)W)[tid + k * 512];   // 4096 exact
            #pragma unroll
            for (int k = 0; k < 8; k++)
                Wb[tid + k * 512] = rne_pack(vw[k].x, vw[k].y);
        }
    }

    int ebase = blk * EPB;
    int epbv = NE - ebase; if (epbv > EPB) epbv = EPB;

    #pragma unroll
    for (int k = 0; k < 8; k++) hist[tid + k * 512] = 0;
    __syncthreads();

    // prefetch dst + src + w 4-deep (latency hides under hist+scan)
    int dloc[4], sloc[4];
    float wloc[4];
    #pragma unroll
    for (int k = 0; k < 4; k++) {
        int i = tid + k * 512;
        bool vld = i < epbv;
        dloc[k] = vld ? dst[ebase + i] : -1;
        sloc[k] = vld ? src[ebase + i] : 0;
        wloc[k] = vld ? w[ebase + i] : 0.f;
    }
    #pragma unroll
    for (int k = 0; k < 4; k++)
        if (dloc[k] >= 0) atomicAdd(&hist[dloc[k] >> 4], 1);
    __syncthreads();

    // exclusive scan of hist[4096]: thread owns 8 CONSECUTIVE sub-buckets
    int b[8], ts = 0;
    #pragma unroll
    for (int k = 0; k < 8; k++) { b[k] = hist[8 * tid + k]; ts += b[k]; }
    int v = ts;
    #pragma unroll
    for (int dd = 1; dd < 64; dd <<= 1) {
        int t = __shfl_up(v, dd);
        if (lane >= dd) v += t;
    }
    if (lane == 63) wsum[wid] = v;
    __syncthreads();
    if (tid < 64) {
        int s = (tid < 8) ? wsum[tid] : 0;
        #pragma unroll
        for (int dd = 1; dd < 8; dd <<= 1) {
            int t = __shfl_up(s, dd);
            if (tid >= dd) s += t;
        }
        if (tid < 8) wsum[tid] = s;
    }
    __syncthreads();
    {
        int base = v - ts + ((wid > 0) ? wsum[wid - 1] : 0);
        unsigned ent[8];
        #pragma unroll
        for (int k = 0; k < 8; k++) {
            cur[8 * tid + k] = base;
            ent[k] = (unsigned)base | ((unsigned)b[k] << 16);
            base += b[k];
        }
        // directory: two coalesced uint4 stores per thread
        uint4* gq = (uint4*)(gidx + (size_t)blk * NSB + 8 * tid);
        gq[0] = make_uint4(ent[0], ent[1], ent[2], ent[3]);
        gq[1] = make_uint4(ent[4], ent[5], ent[6], ent[7]);
    }
    __syncthreads();

    // placement DIRECT to block-private global region
    uint2* regn = gsegB + (size_t)blk * REG;
    #pragma unroll
    for (int k = 0; k < 4; k++) {
        if (dloc[k] >= 0) {
            int d = dloc[k];
            unsigned rec = ((unsigned)sloc[k] << 16) |
                           (unsigned)__half_as_ushort(__float2half(wloc[k]));
            int pos = atomicAdd(&cur[d >> 4], 1);
            regn[pos] = make_uint2(rec, (unsigned)(d & 15));
        }
    }
}

// ---------------------------------------------------------------------------
// K2: R15 body with the (256,8) clamp REMOVED (single-variable fix).
// R15's counters proved the clamp spilled: VGPR=32, FETCH 117MB, WRITE
// 62.5MB (scratch traffic).  Unclamped, the 2-node/8-gather interleave gets
// its fair test at ~60-70 VGPR (>= 6 blocks/CU, still 9x oversubscribed).
// ---------------------------------------------------------------------------
__global__ __launch_bounds__(256) void k_fused(const unsigned* __restrict__ hb,
                                               const unsigned* __restrict__ gidx,
                                               const uint2* __restrict__ gsegB,
                                               const unsigned* __restrict__ Wb,
                                               const float* __restrict__ b,
                                               float* __restrict__ out)
{
    __shared__ unsigned slots[SNODES * SLOTS];                 // 3072B
    __shared__ __align__(16) unsigned short hNl[SNODES * 72];  // 2304B
    __shared__ int deg[SNODES];

    int tid  = threadIdx.x;
    int lane = tid & 63;
    int wv   = __builtin_amdgcn_readfirstlane(tid >> 6);
    int nbase = blockIdx.x * SNODES;        // 3125*16 = 50000 exact, no tail
    int sb    = blockIdx.x;                 // sub-bucket == block (1:1)

    int m    = lane & 15;                   // node row within tile / B col
    int quad = lane >> 4;
    int j    = wv * 16 + m;                 // out feature owned by this lane
    int ng   = nbase + m;

    // hoisted loop-invariant loads (issue before phase A; no later stall)
    short8 bf[4];
    #pragma unroll
    for (int kk = 0; kk < 4; kk++) {
        uint4 bw = *(const uint4*)(Wb + (size_t)j * 64 + kk * 16 + quad * 4);
        bf[kk] = *(short8*)&bw;
    }
    float bv = b[j];
    uint4 t0 = *(const uint4*)(hb + (size_t)ng * 32 + 0 * 16 + quad * 4);
    uint4 t1 = *(const uint4*)(hb + (size_t)ng * 32 + 1 * 16 + quad * 4);

    // strided directory reads (row-major gidx), issued before deg init
    unsigned e0 = gidx[(size_t)(2 * tid)     * NSB + sb];
    unsigned e1 = gidx[(size_t)(2 * tid + 1) * NSB + sb];

    if (tid < SNODES) deg[tid] = 0;
    __syncthreads();

    // ---- phase A: walk 512 lambda~0.5 runs, 2/thread, no filter ----
    {
        int c0 = (int)(e0 >> 16), c1 = (int)(e1 >> 16);
        const uint2* r0 = gsegB + (size_t)(2 * tid)     * REG + (e0 & 0xFFFFu);
        const uint2* r1 = gsegB + (size_t)(2 * tid + 1) * REG + (e1 & 0xFFFFu);
        int n = max(c0, c1);
        for (int k = 0; k < n; k++) {
            uint2 a, c;
            bool va = k < c0, vb = k < c1;
            if (va) a = r0[k];
            if (vb) c = r1[k];
            if (va) {
                int p = atomicAdd(&deg[a.y], 1);
                if (p < SLOTS) slots[a.y * SLOTS + p] = a.x;
            }
            if (vb) {
                int p = atomicAdd(&deg[c.y], 1);
                if (p < SLOTS) slots[c.y * SLOTS + p] = c.x;
            }
        }
    }
    __syncthreads();

    // ---- phase B: two nodes per iteration, 8 gathers in flight ----
    int g = lane >> 4, q = lane & 15;
    #pragma unroll 1
    for (int p2 = 0; p2 < 2; p2++) {
        int la = wv * 4 + 2 * p2;
        int lb = la + 1;
        int dga = deg[la], dgb = deg[lb];
        int ma = min(dga, SLOTS), mb = min(dgb, SLOTS);
        const unsigned* sa = &slots[la * SLOTS];
        const unsigned* sbp = &slots[lb * SLOTS];
        float4 accA = make_float4(0.f, 0.f, 0.f, 0.f);
        float4 accB = make_float4(0.f, 0.f, 0.f, 0.f);
        int n = max(ma, mb);
        #pragma unroll 1
        for (int cb = 0; cb < n; cb += 16) {
            float wa[4], wb2[4];
            uint2 ha[4], hbv[4];
            // issue ALL 8 gathers (4 per node) before any accumulate
            #pragma unroll
            for (int jj = 0; jj < 4; jj++) {
                int ii = cb + jj * 4 + g;       // <= 47 < SLOTS always
                bool va = ii < ma;
                unsigned ra = sa[ii];
                wa[jj] = va ? __half2float(__ushort_as_half(
                                  (unsigned short)(ra & 0xFFFFu))) : 0.f;
                int s = va ? (int)(ra >> 16) : 0;
                ha[jj] = *(const uint2*)(hb + (size_t)s * 32 + q * 2);
            }
            #pragma unroll
            for (int jj = 0; jj < 4; jj++) {
                int ii = cb + jj * 4 + g;
                bool vb = ii < mb;
                unsigned rb = sbp[ii];
                wb2[jj] = vb ? __half2float(__ushort_as_half(
                                   (unsigned short)(rb & 0xFFFFu))) : 0.f;
                int s = vb ? (int)(rb >> 16) : 0;
                hbv[jj] = *(const uint2*)(hb + (size_t)s * 32 + q * 2);
            }
            #pragma unroll
            for (int jj = 0; jj < 4; jj++) {
                accA.x += wa[jj] * __uint_as_float(ha[jj].x << 16);
                accA.y += wa[jj] * __uint_as_float(ha[jj].x & 0xFFFF0000u);
                accA.z += wa[jj] * __uint_as_float(ha[jj].y << 16);
                accA.w += wa[jj] * __uint_as_float(ha[jj].y & 0xFFFF0000u);
            }
            #pragma unroll
            for (int jj = 0; jj < 4; jj++) {
                accB.x += wb2[jj] * __uint_as_float(hbv[jj].x << 16);
                accB.y += wb2[jj] * __uint_as_float(hbv[jj].x & 0xFFFF0000u);
                accB.z += wb2[jj] * __uint_as_float(hbv[jj].y << 16);
                accB.w += wb2[jj] * __uint_as_float(hbv[jj].y & 0xFFFF0000u);
            }
        }
        // reduce both nodes across the 4 groups
        accA.x += __shfl_xor(accA.x, 16); accA.y += __shfl_xor(accA.y, 16);
        accA.z += __shfl_xor(accA.z, 16); accA.w += __shfl_xor(accA.w, 16);
        accA.x += __shfl_xor(accA.x, 32); accA.y += __shfl_xor(accA.y, 32);
        accA.z += __shfl_xor(accA.z, 32); accA.w += __shfl_xor(accA.w, 32);
        accB.x += __shfl_xor(accB.x, 16); accB.y += __shfl_xor(accB.y, 16);
        accB.z += __shfl_xor(accB.z, 16); accB.w += __shfl_xor(accB.w, 16);
        accB.x += __shfl_xor(accB.x, 32); accB.y += __shfl_xor(accB.y, 32);
        accB.z += __shfl_xor(accB.z, 32); accB.w += __shfl_xor(accB.w, 32);
        if (g == 0) {
            float invA = 1.0f / fmaxf((float)dga, 1.0f);
            uint2 oA;
            oA.x = rne_pack(accA.x * invA, accA.y * invA);
            oA.y = rne_pack(accA.z * invA, accA.w * invA);
            *(uint2*)&hNl[la * 72 + q * 4] = oA;
            float invB = 1.0f / fmaxf((float)dgb, 1.0f);
            uint2 oB;
            oB.x = rne_pack(accB.x * invB, accB.y * invB);
            oB.y = rne_pack(accB.z * invB, accB.w * invB);
            *(uint2*)&hNl[lb * 72 + q * 4] = oB;
        }
    }
    __syncthreads();

    // ---- phase C: MFMA GEMM; all waves share A-rows, wave = 16 out-feats --
    {
        short8 a[4];
        {
            uint4 t2 = *(const uint4*)&hNl[m * 72 + 0 * 32 + quad * 8];
            uint4 t3 = *(const uint4*)&hNl[m * 72 + 1 * 32 + quad * 8];
            a[0] = *(short8*)&t0; a[1] = *(short8*)&t1;
            a[2] = *(short8*)&t2; a[3] = *(short8*)&t3;
        }

        f32x4 acc = {bv, bv, bv, bv};
        #pragma unroll
        for (int kk = 0; kk < 4; kk++)
            acc = __builtin_amdgcn_mfma_f32_16x16x32_bf16(a[kk], bf[kk],
                                                          acc, 0, 0, 0);
        #pragma unroll
        for (int r = 0; r < 4; r++) {
            int lrow = quad * 4 + r;        // D: col=lane&15, row=quad*4+r
            out[(size_t)(nbase + lrow) * 64 + j] = acc[r];
        }
    }
}

extern "C" void kernel_launch(void* const* d_in, const int* in_sizes, int n_in,
                              void* d_out, int out_size, void* d_ws, size_t ws_size,
                              hipStream_t stream) {
    const float* h   = (const float*)d_in[0];
    const float* w   = (const float*)d_in[1];
    const int*   src = (const int*)d_in[2];
    const int*   dst = (const int*)d_in[3];
    const float* W   = (const float*)d_in[4];
    const float* b   = (const float*)d_in[5];
    float* out = (float*)d_out;

    // workspace: hb 6.4MB + Wb 16KB + gidx 8MB + gsegB 6.4MB = ~20.9MB
    char* p = (char*)d_ws;
    unsigned* hb   = (unsigned*)p;  p += (size_t)(NN * D / 2) * 4;
    unsigned* Wb   = (unsigned*)p;  p += (size_t)(64 * 128 / 2) * 4;
    unsigned* gidx = (unsigned*)p;  p += (size_t)K1BLK * NSB * 4;
    uint2* gsegB   = (uint2*)p;     // K1BLK * REG * 8 = 6,422,528 bytes

    k_bucket<<<K1BLK, 512, 0, stream>>>(dst, src, w, h, W, hb, Wb,
                                        gidx, gsegB);

    k_fused <<<K2BLK, 256, 0, stream>>>(hb, gidx, gsegB, Wb, b, out);
}